// Round 1
// baseline (139.442 us; speedup 1.0000x reference)
//
#include <hip/hip_runtime.h>
#include <hip/hip_bf16.h>
#include <math.h>

typedef __attribute__((ext_vector_type(4))) float f32x4;
typedef __attribute__((ext_vector_type(8))) short bf16x8;

#define NB    64
#define LQ    32
#define LDOC  256
#define HDIM  768
#define DDIM  128
#define NTOK_Q (NB * LQ)        // 2048
#define NTOK_D (NB * LDOC)      // 16384
#define NTOK   (NTOK_Q + NTOK_D) // 18432

// ws layout (bytes):
//   [0,        196608)  Wbf   : 128*768 bf16
//   [196608,   212992)  mask8 : 16384 uint8
//   [212992,   737280)  Qn    : 2048*128 bf16
//   [737280,  4931584)  Dn    : 16384*128 bf16
#define WS_OFF_W    0
#define WS_OFF_MASK 196608
#define WS_OFF_QN   212992
#define WS_OFF_DN   737280

__device__ inline short f2bf(float f) {
    unsigned u = __float_as_uint(f);
    u = (u + 0x7fffu + ((u >> 16) & 1u)) >> 16;   // RNE
    return (short)u;
}

// ---------------------------------------------------------------------------
// Detect the on-device layout of the bool mask (1-byte bool vs 4-byte int/float)
// and expand to canonical uint8[16384]. Deterministic (pure function of input).
__global__ void mask_prep(const unsigned char* __restrict__ mraw,
                          unsigned char* __restrict__ mask8) {
    __shared__ int dword_ok_s;
    if (threadIdx.x == 0) dword_ok_s = 1;
    __syncthreads();
    const unsigned* dw = (const unsigned*)mraw;
    int ok = 1;
    // Only touch the first 16384 bytes (safe under both layouts).
    for (int i = threadIdx.x; i < 4096; i += 256) {
        unsigned v = dw[i];
        if (!(v == 0u || v == 1u || v == 0x3F800000u)) ok = 0;
    }
    if (!ok) atomicAnd(&dword_ok_s, 0);
    __syncthreads();
    if (dword_ok_s) {          // 4-byte elements (int32 0/1 or float32 0.0/1.0)
        for (int i = threadIdx.x; i < NTOK_D; i += 256)
            mask8[i] = dw[i] ? 1 : 0;
    } else {                   // 1-byte bool
        for (int i = threadIdx.x; i < NTOK_D; i += 256)
            mask8[i] = mraw[i] ? 1 : 0;
    }
}

// ---------------------------------------------------------------------------
// W fp32 -> bf16 (128x768)
__global__ void wconv(const float* __restrict__ W, short* __restrict__ Wbf) {
    int i = blockIdx.x * 256 + threadIdx.x;     // 24576 threads, 4 elems each
    float4 v = *(const float4*)(W + (size_t)i * 4);
    short4 o;
    o.x = f2bf(v.x); o.y = f2bf(v.y); o.z = f2bf(v.z); o.w = f2bf(v.w);
    *(short4*)(Wbf + (size_t)i * 4) = o;
}

// ---------------------------------------------------------------------------
// Projection + L2 norm: C[18432,128] = X[18432,768] . W^T, rows normalized,
// stored bf16 into Qn / Dn. One wave = 16 rows x full N=128. 4 waves/block.
__global__ __launch_bounds__(256)
void proj_norm(const float* __restrict__ Qh, const float* __restrict__ Dh,
               const short* __restrict__ Wbf,
               short* __restrict__ Qn, short* __restrict__ Dn) {
    const int lane = threadIdx.x & 63;
    const int wave = threadIdx.x >> 6;
    const int g    = lane >> 4;      // k-subblock for A/B frags; row-group for C
    const int lc   = lane & 15;      // A-row / B-col for frags; C-col

    const int rowA = blockIdx.x * 64 + wave * 16 + lc;   // A-load row
    const float* src = (rowA < NTOK_Q) ? (Qh + (size_t)rowA * HDIM)
                                       : (Dh + (size_t)(rowA - NTOK_Q) * HDIM);

    f32x4 acc[8];
#pragma unroll
    for (int nt = 0; nt < 8; ++nt) acc[nt] = (f32x4){0.f, 0.f, 0.f, 0.f};

    for (int k = 0; k < HDIM; k += 32) {
        const int kk = k + g * 8;
        float4 a0 = *(const float4*)(src + kk);
        float4 a1 = *(const float4*)(src + kk + 4);
        bf16x8 af;
        af[0] = f2bf(a0.x); af[1] = f2bf(a0.y); af[2] = f2bf(a0.z); af[3] = f2bf(a0.w);
        af[4] = f2bf(a1.x); af[5] = f2bf(a1.y); af[6] = f2bf(a1.z); af[7] = f2bf(a1.w);
#pragma unroll
        for (int nt = 0; nt < 8; ++nt) {
            bf16x8 bv = *(const bf16x8*)(Wbf + (size_t)(nt * 16 + lc) * HDIM + kk);
            acc[nt] = __builtin_amdgcn_mfma_f32_16x16x32_bf16(af, bv, acc[nt], 0, 0, 0);
        }
    }

    // C/D layout: col = lane&15, row = (lane>>4)*4 + i  [m89/m91 verified]
    const int rowBase = blockIdx.x * 64 + wave * 16;
#pragma unroll
    for (int i = 0; i < 4; ++i) {
        float s = 0.f;
#pragma unroll
        for (int nt = 0; nt < 8; ++nt) s += acc[nt][i] * acc[nt][i];
        s += __shfl_xor(s, 1);
        s += __shfl_xor(s, 2);
        s += __shfl_xor(s, 4);
        s += __shfl_xor(s, 8);
        const float inv = 1.f / fmaxf(sqrtf(s), 1e-12f);
        const int r = rowBase + 4 * g + i;
        short* dst = (r < NTOK_Q) ? (Qn + (size_t)r * DDIM)
                                  : (Dn + (size_t)(r - NTOK_Q) * DDIM);
#pragma unroll
        for (int nt = 0; nt < 8; ++nt)
            dst[nt * 16 + lc] = f2bf(acc[nt][i] * inv);
    }
}

// ---------------------------------------------------------------------------
// MaxSim: one block per (b,c). 2 waves, each wave owns 16 q-rows x all 256 n.
__global__ __launch_bounds__(128)
void maxsim(const short* __restrict__ Qn, const short* __restrict__ Dn,
            const unsigned char* __restrict__ mask8, float* __restrict__ out) {
    const int c = blockIdx.x >> 6;    // c-major: consecutive blocks share D[c]
    const int b = blockIdx.x & 63;
    const int wave = threadIdx.x >> 6;
    const int lane = threadIdx.x & 63;
    const int g = lane >> 4, lc = lane & 15;

    // Q fragments for this wave's 16 q-rows, all K=128 (4 k-steps) in regs
    bf16x8 af[4];
    const short* qbase = Qn + (size_t)(b * LQ + wave * 16 + lc) * DDIM;
#pragma unroll
    for (int ks = 0; ks < 4; ++ks)
        af[ks] = *(const bf16x8*)(qbase + ks * 32 + g * 8);

    float rmax[4] = {-INFINITY, -INFINITY, -INFINITY, -INFINITY};
    const short* dbase = Dn + (size_t)c * LDOC * DDIM;
    const unsigned char* mk = mask8 + c * LDOC;

    for (int nt = 0; nt < 16; ++nt) {
        const short* drow = dbase + (size_t)(nt * 16 + lc) * DDIM;
        f32x4 acc = (f32x4){0.f, 0.f, 0.f, 0.f};
#pragma unroll
        for (int ks = 0; ks < 4; ++ks) {
            bf16x8 bv = *(const bf16x8*)(drow + ks * 32 + g * 8);
            acc = __builtin_amdgcn_mfma_f32_16x16x32_bf16(af[ks], bv, acc, 0, 0, 0);
        }
        if (mk[nt * 16 + lc]) {       // mask depends only on C-col (= lane&15)
#pragma unroll
            for (int i = 0; i < 4; ++i) rmax[i] = fmaxf(rmax[i], acc[i]);
        }
    }

    // max over 16 cols within lane-group, then sum the 4 rows this group owns
    float s = 0.f;
#pragma unroll
    for (int i = 0; i < 4; ++i) {
        float m = rmax[i];
        m = fmaxf(m, __shfl_xor(m, 1));
        m = fmaxf(m, __shfl_xor(m, 2));
        m = fmaxf(m, __shfl_xor(m, 4));
        m = fmaxf(m, __shfl_xor(m, 8));
        s += m;
    }
    s += __shfl_xor(s, 16);   // sum across the 4 row-groups
    s += __shfl_xor(s, 32);

    __shared__ float red[2];
    if (lane == 0) red[wave] = s;
    __syncthreads();
    if (threadIdx.x == 0) out[(size_t)b * NB + c] = red[0] + red[1];
}

// ---------------------------------------------------------------------------
extern "C" void kernel_launch(void* const* d_in, const int* in_sizes, int n_in,
                              void* d_out, int out_size, void* d_ws, size_t ws_size,
                              hipStream_t stream) {
    const float* Qh = (const float*)d_in[0];
    const float* Dh = (const float*)d_in[1];
    const float* W  = (const float*)d_in[2];
    const unsigned char* dm = (const unsigned char*)d_in[3];
    float* out = (float*)d_out;
    char* ws = (char*)d_ws;

    short*         Wbf   = (short*)(ws + WS_OFF_W);
    unsigned char* mask8 = (unsigned char*)(ws + WS_OFF_MASK);
    short*         Qn    = (short*)(ws + WS_OFF_QN);
    short*         Dn    = (short*)(ws + WS_OFF_DN);

    mask_prep<<<1, 256, 0, stream>>>(dm, mask8);
    wconv<<<96, 256, 0, stream>>>(W, Wbf);
    proj_norm<<<NTOK / 64, 256, 0, stream>>>(Qh, Dh, Wbf, Qn, Dn);
    maxsim<<<NB * NB, 128, 0, stream>>>(Qn, Dn, mask8, out);
}

// Round 2
// 110.150 us; speedup vs baseline: 1.2659x; 1.2659x over previous
//
#include <hip/hip_runtime.h>
#include <hip/hip_bf16.h>
#include <math.h>

typedef __attribute__((ext_vector_type(4))) float f32x4;
typedef __attribute__((ext_vector_type(8))) short bf16x8;

#define NB    64
#define LQ    32
#define LDOC  256
#define HDIM  768
#define DDIM  128
#define NTOK_Q (NB * LQ)        // 2048
#define NTOK_D (NB * LDOC)      // 16384
#define NTOK   (NTOK_Q + NTOK_D) // 18432

#define KCH    128              // K-chunk staged per iteration
#define NCHUNK (HDIM / KCH)     // 6
#define ASTRIDE 136             // LDS row stride in shorts (272 B = 17*16B, conflict-light)

// ws layout (bytes):
#define WS_OFF_W    0           // Wbf   : 128*768 bf16   (196608)
#define WS_OFF_MASK 196608      // mask8 : 16384 uint8
#define WS_OFF_QN   212992      // Qn    : 2048*128 bf16
#define WS_OFF_DN   737280      // Dn    : 16384*128 bf16

__device__ inline short f2bf(float f) {
    unsigned u = __float_as_uint(f);
    u = (u + 0x7fffu + ((u >> 16) & 1u)) >> 16;   // RNE
    return (short)u;
}

// ---------------------------------------------------------------------------
// Expand bool mask to canonical uint8[16384]; detect 1-byte vs 4-byte layout
// from the data itself (pure function of input -> deterministic).
__global__ void mask_prep(const unsigned char* __restrict__ mraw,
                          unsigned char* __restrict__ mask8) {
    __shared__ int dword_ok_s;
    if (threadIdx.x == 0) dword_ok_s = 1;
    __syncthreads();
    const unsigned* dw = (const unsigned*)mraw;
    int ok = 1;
    for (int i = threadIdx.x; i < 4096; i += 256) {   // first 16384 bytes: safe both ways
        unsigned v = dw[i];
        if (!(v == 0u || v == 1u || v == 0x3F800000u)) ok = 0;
    }
    if (!ok) atomicAnd(&dword_ok_s, 0);
    __syncthreads();
    const int base = blockIdx.x * 1024;
    if (dword_ok_s) {
        for (int i = threadIdx.x; i < 1024; i += 256)
            mask8[base + i] = dw[base + i] ? 1 : 0;
    } else {
        for (int i = threadIdx.x; i < 1024; i += 256)
            mask8[base + i] = mraw[base + i] ? 1 : 0;
    }
}

// ---------------------------------------------------------------------------
// W fp32 -> bf16 (128x768)
__global__ void wconv(const float* __restrict__ W, short* __restrict__ Wbf) {
    int i = blockIdx.x * 256 + threadIdx.x;
    float4 v = *(const float4*)(W + (size_t)i * 4);
    short4 o;
    o.x = f2bf(v.x); o.y = f2bf(v.y); o.z = f2bf(v.z); o.w = f2bf(v.w);
    *(short4*)(Wbf + (size_t)i * 4) = o;
}

// ---------------------------------------------------------------------------
// Projection + L2 norm, v2: block = 16 rows x 128 cols, 4 waves split N
// (each wave 16x32, full K). A staged to double-buffered LDS bf16 tile.
__global__ __launch_bounds__(256)
void proj_norm(const float* __restrict__ Qh, const float* __restrict__ Dh,
               const short* __restrict__ Wbf,
               short* __restrict__ Qn, short* __restrict__ Dn) {
    const int lane = threadIdx.x & 63;
    const int wave = threadIdx.x >> 6;
    const int g    = lane >> 4;
    const int lc   = lane & 15;
    const int row0 = blockIdx.x * 16;

    __shared__ short As[2][16][ASTRIDE];
    __shared__ float norms[4][16];

    // cooperative A-load assignment: thread t -> row t>>4, cols (t&15)*8 (32 B)
    const int lrow = threadIdx.x >> 4;
    const int lcol = (threadIdx.x & 15) * 8;
    const int grow = row0 + lrow;
    const float* srcRow = (grow < NTOK_Q) ? Qh + (size_t)grow * HDIM
                                          : Dh + (size_t)(grow - NTOK_Q) * HDIM;

    // B bases for this wave's two 16-col n-tiles
    const short* w0 = Wbf + (size_t)(wave * 32 + lc) * HDIM;
    const short* w1 = Wbf + (size_t)(wave * 32 + 16 + lc) * HDIM;

    // prologue: stage chunk 0
    float4 p0 = *(const float4*)(srcRow + lcol);
    float4 p1 = *(const float4*)(srcRow + lcol + 4);
    {
        short* d = &As[0][lrow][lcol];
        short4 o0, o1;
        o0.x = f2bf(p0.x); o0.y = f2bf(p0.y); o0.z = f2bf(p0.z); o0.w = f2bf(p0.w);
        o1.x = f2bf(p1.x); o1.y = f2bf(p1.y); o1.z = f2bf(p1.z); o1.w = f2bf(p1.w);
        *(short4*)d = o0; *(short4*)(d + 4) = o1;
    }
    __syncthreads();

    f32x4 acc[2];
    acc[0] = (f32x4){0.f, 0.f, 0.f, 0.f};
    acc[1] = (f32x4){0.f, 0.f, 0.f, 0.f};

#pragma unroll
    for (int ch = 0; ch < NCHUNK; ++ch) {
        if (ch < NCHUNK - 1) {   // issue next chunk's loads early (hide under MFMA)
            p0 = *(const float4*)(srcRow + (ch + 1) * KCH + lcol);
            p1 = *(const float4*)(srcRow + (ch + 1) * KCH + lcol + 4);
        }
        const short* abase = &As[ch & 1][lc][0];
#pragma unroll
        for (int ks = 0; ks < 4; ++ks) {
            bf16x8 af = *(const bf16x8*)(abase + ks * 32 + g * 8);
            const int ko = ch * KCH + ks * 32 + g * 8;
            acc[0] = __builtin_amdgcn_mfma_f32_16x16x32_bf16(
                         af, *(const bf16x8*)(w0 + ko), acc[0], 0, 0, 0);
            acc[1] = __builtin_amdgcn_mfma_f32_16x16x32_bf16(
                         af, *(const bf16x8*)(w1 + ko), acc[1], 0, 0, 0);
        }
        if (ch < NCHUNK - 1) {
            // all waves' reads of buf[(ch+1)&1] finished before the iter-(ch-1)
            // end barrier; safe to overwrite now, then barrier before use.
            short* d = &As[(ch + 1) & 1][lrow][lcol];
            short4 o0, o1;
            o0.x = f2bf(p0.x); o0.y = f2bf(p0.y); o0.z = f2bf(p0.z); o0.w = f2bf(p0.w);
            o1.x = f2bf(p1.x); o1.y = f2bf(p1.y); o1.z = f2bf(p1.z); o1.w = f2bf(p1.w);
            *(short4*)d = o0; *(short4*)(d + 4) = o1;
            __syncthreads();
        }
    }

    // per-row sum of squares: in-lane over 2 n-tiles, shuffle over 16 cols,
    // LDS over 4 waves
    float p[4];
#pragma unroll
    for (int i = 0; i < 4; ++i) {
        float s = acc[0][i] * acc[0][i] + acc[1][i] * acc[1][i];
        s += __shfl_xor(s, 1);
        s += __shfl_xor(s, 2);
        s += __shfl_xor(s, 4);
        s += __shfl_xor(s, 8);
        p[i] = s;
    }
    __syncthreads();          // As reads done everywhere; reuse barrier for norms
    if (lc == 0) {
#pragma unroll
        for (int i = 0; i < 4; ++i) norms[wave][g * 4 + i] = p[i];
    }
    __syncthreads();

#pragma unroll
    for (int i = 0; i < 4; ++i) {
        const int rloc = g * 4 + i;
        const float tot = norms[0][rloc] + norms[1][rloc] + norms[2][rloc] + norms[3][rloc];
        const float inv = 1.f / fmaxf(sqrtf(tot), 1e-12f);
        const int r = row0 + rloc;
        short* dst = (r < NTOK_Q) ? (Qn + (size_t)r * DDIM)
                                  : (Dn + (size_t)(r - NTOK_Q) * DDIM);
        dst[wave * 32 + lc]      = f2bf(acc[0][i] * inv);
        dst[wave * 32 + 16 + lc] = f2bf(acc[1][i] * inv);
    }
}

// ---------------------------------------------------------------------------
// MaxSim: one block per (b,c); XCD-aware mapping puts all 64 blocks of a c on
// one XCD (8 c's / XCD -> 512 KB Dn working set per L2).
__global__ __launch_bounds__(128)
void maxsim(const short* __restrict__ Qn, const short* __restrict__ Dn,
            const unsigned char* __restrict__ mask8, float* __restrict__ out) {
    const int x    = blockIdx.x & 7;          // presumed XCD (perf-only heuristic)
    const int slot = blockIdx.x >> 3;         // 0..511
    const int c    = x * 8 + (slot >> 6);
    const int b    = slot & 63;

    const int wave = threadIdx.x >> 6;
    const int lane = threadIdx.x & 63;
    const int g = lane >> 4, lc = lane & 15;

    bf16x8 af[4];
    const short* qbase = Qn + (size_t)(b * LQ + wave * 16 + lc) * DDIM;
#pragma unroll
    for (int ks = 0; ks < 4; ++ks)
        af[ks] = *(const bf16x8*)(qbase + ks * 32 + g * 8);

    float rmax[4] = {-INFINITY, -INFINITY, -INFINITY, -INFINITY};
    const short* dbase = Dn + (size_t)c * LDOC * DDIM;
    const unsigned char* mk = mask8 + c * LDOC;

    for (int nt = 0; nt < 16; ++nt) {
        const short* drow = dbase + (size_t)(nt * 16 + lc) * DDIM;
        f32x4 acc = (f32x4){0.f, 0.f, 0.f, 0.f};
#pragma unroll
        for (int ks = 0; ks < 4; ++ks) {
            bf16x8 bv = *(const bf16x8*)(drow + ks * 32 + g * 8);
            acc = __builtin_amdgcn_mfma_f32_16x16x32_bf16(af[ks], bv, acc, 0, 0, 0);
        }
        if (mk[nt * 16 + lc]) {
#pragma unroll
            for (int i = 0; i < 4; ++i) rmax[i] = fmaxf(rmax[i], acc[i]);
        }
    }

    float s = 0.f;
#pragma unroll
    for (int i = 0; i < 4; ++i) {
        float m = rmax[i];
        m = fmaxf(m, __shfl_xor(m, 1));
        m = fmaxf(m, __shfl_xor(m, 2));
        m = fmaxf(m, __shfl_xor(m, 4));
        m = fmaxf(m, __shfl_xor(m, 8));
        s += m;
    }
    s += __shfl_xor(s, 16);
    s += __shfl_xor(s, 32);

    __shared__ float red[2];
    if (lane == 0) red[wave] = s;
    __syncthreads();
    if (threadIdx.x == 0) out[(size_t)b * NB + c] = red[0] + red[1];
}

// ---------------------------------------------------------------------------
extern "C" void kernel_launch(void* const* d_in, const int* in_sizes, int n_in,
                              void* d_out, int out_size, void* d_ws, size_t ws_size,
                              hipStream_t stream) {
    const float* Qh = (const float*)d_in[0];
    const float* Dh = (const float*)d_in[1];
    const float* W  = (const float*)d_in[2];
    const unsigned char* dm = (const unsigned char*)d_in[3];
    float* out = (float*)d_out;
    char* ws = (char*)d_ws;

    short*         Wbf   = (short*)(ws + WS_OFF_W);
    unsigned char* mask8 = (unsigned char*)(ws + WS_OFF_MASK);
    short*         Qn    = (short*)(ws + WS_OFF_QN);
    short*         Dn    = (short*)(ws + WS_OFF_DN);

    mask_prep<<<16, 256, 0, stream>>>(dm, mask8);
    wconv<<<96, 256, 0, stream>>>(W, Wbf);
    proj_norm<<<NTOK / 16, 256, 0, stream>>>(Qh, Dh, Wbf, Qn, Dn);
    maxsim<<<NB * NB, 128, 0, stream>>>(Qn, Dn, mask8, out);
}

// Round 3
// 62.208 us; speedup vs baseline: 2.2416x; 1.7707x over previous
//
#include <hip/hip_runtime.h>
#include <hip/hip_bf16.h>
#include <math.h>

typedef __attribute__((ext_vector_type(4))) float f32x4;
typedef __attribute__((ext_vector_type(8))) short bf16x8;

#define NB    64
#define LQ    32
#define LDOC  256
#define HDIM  768
#define DDIM  128
#define NTOK_Q (NB * LQ)        // 2048
#define NTOK_D (NB * LDOC)      // 16384
#define NTOK   (NTOK_Q + NTOK_D) // 18432

#define KCH    128              // proj: K-chunk staged per iteration
#define NCHUNK (HDIM / KCH)     // 6
#define ASTRIDE 136             // proj LDS row stride in shorts

// ws layout (bytes):
#define WS_OFF_W    0           // Wbf   : 128*768 bf16   (196608)
#define WS_OFF_MASK 196608      // maskT : 64*16 ushort (2KB)
#define WS_OFF_QN   212992      // Qn    : 2048*128 bf16
#define WS_OFF_DN   737280      // Dn    : 16384*128 bf16

__device__ inline short f2bf(float f) {
    unsigned u = __float_as_uint(f);
    u = (u + 0x7fffu + ((u >> 16) & 1u)) >> 16;   // RNE
    return (short)u;
}

// ---------------------------------------------------------------------------
// prep: blocks 0..95 convert W fp32->bf16; block 96 builds bit-transposed mask.
// Mask layout (1B bool vs 4B int/float) detected from data (deterministic).
__global__ void prep(const float* __restrict__ W, short* __restrict__ Wbf,
                     const unsigned char* __restrict__ mraw,
                     unsigned short* __restrict__ maskT) {
    if (blockIdx.x < 96) {
        int i = blockIdx.x * 256 + threadIdx.x;
        float4 v = *(const float4*)(W + (size_t)i * 4);
        short4 o;
        o.x = f2bf(v.x); o.y = f2bf(v.y); o.z = f2bf(v.z); o.w = f2bf(v.w);
        *(short4*)(Wbf + (size_t)i * 4) = o;
        return;
    }
    __shared__ int dword_ok_s;
    if (threadIdx.x == 0) dword_ok_s = 1;
    __syncthreads();
    const unsigned* dw = (const unsigned*)mraw;
    int ok = 1;
    for (int i = threadIdx.x; i < 4096; i += 256) {   // first 16KB: safe both ways
        unsigned v = dw[i];
        if (!(v == 0u || v == 1u || v == 0x3F800000u)) ok = 0;
    }
    if (!ok) atomicAnd(&dword_ok_s, 0);
    __syncthreads();
    const int isdw = dword_ok_s;
    for (int w = threadIdx.x; w < 1024; w += 256) {   // word w: c=w>>4, lane-col=w&15
        const int c = w >> 4, lcc = w & 15;
        unsigned bits = 0;
        if (isdw) {
            for (int nt = 0; nt < 16; ++nt)
                bits |= (dw[c * 256 + nt * 16 + lcc] ? 1u : 0u) << nt;
        } else {
            for (int nt = 0; nt < 16; ++nt)
                bits |= (mraw[c * 256 + nt * 16 + lcc] ? 1u : 0u) << nt;
        }
        maskT[w] = (unsigned short)bits;
    }
}

// ---------------------------------------------------------------------------
// Projection + L2 norm: block = 16 rows x 128 cols, 4 waves split N.
__global__ __launch_bounds__(256)
void proj_norm(const float* __restrict__ Qh, const float* __restrict__ Dh,
               const short* __restrict__ Wbf,
               short* __restrict__ Qn, short* __restrict__ Dn) {
    const int lane = threadIdx.x & 63;
    const int wave = threadIdx.x >> 6;
    const int g    = lane >> 4;
    const int lc   = lane & 15;
    const int row0 = blockIdx.x * 16;

    __shared__ short As[2][16][ASTRIDE];
    __shared__ float norms[4][16];

    const int lrow = threadIdx.x >> 4;
    const int lcol = (threadIdx.x & 15) * 8;
    const int grow = row0 + lrow;
    const float* srcRow = (grow < NTOK_Q) ? Qh + (size_t)grow * HDIM
                                          : Dh + (size_t)(grow - NTOK_Q) * HDIM;

    const short* w0 = Wbf + (size_t)(wave * 32 + lc) * HDIM;
    const short* w1 = Wbf + (size_t)(wave * 32 + 16 + lc) * HDIM;

    float4 p0 = *(const float4*)(srcRow + lcol);
    float4 p1 = *(const float4*)(srcRow + lcol + 4);
    {
        short* d = &As[0][lrow][lcol];
        short4 o0, o1;
        o0.x = f2bf(p0.x); o0.y = f2bf(p0.y); o0.z = f2bf(p0.z); o0.w = f2bf(p0.w);
        o1.x = f2bf(p1.x); o1.y = f2bf(p1.y); o1.z = f2bf(p1.z); o1.w = f2bf(p1.w);
        *(short4*)d = o0; *(short4*)(d + 4) = o1;
    }
    __syncthreads();

    f32x4 acc[2];
    acc[0] = (f32x4){0.f, 0.f, 0.f, 0.f};
    acc[1] = (f32x4){0.f, 0.f, 0.f, 0.f};

#pragma unroll
    for (int ch = 0; ch < NCHUNK; ++ch) {
        if (ch < NCHUNK - 1) {
            p0 = *(const float4*)(srcRow + (ch + 1) * KCH + lcol);
            p1 = *(const float4*)(srcRow + (ch + 1) * KCH + lcol + 4);
        }
        const short* abase = &As[ch & 1][lc][0];
#pragma unroll
        for (int ks = 0; ks < 4; ++ks) {
            bf16x8 af = *(const bf16x8*)(abase + ks * 32 + g * 8);
            const int ko = ch * KCH + ks * 32 + g * 8;
            acc[0] = __builtin_amdgcn_mfma_f32_16x16x32_bf16(
                         af, *(const bf16x8*)(w0 + ko), acc[0], 0, 0, 0);
            acc[1] = __builtin_amdgcn_mfma_f32_16x16x32_bf16(
                         af, *(const bf16x8*)(w1 + ko), acc[1], 0, 0, 0);
        }
        if (ch < NCHUNK - 1) {
            short* d = &As[(ch + 1) & 1][lrow][lcol];
            short4 o0, o1;
            o0.x = f2bf(p0.x); o0.y = f2bf(p0.y); o0.z = f2bf(p0.z); o0.w = f2bf(p0.w);
            o1.x = f2bf(p1.x); o1.y = f2bf(p1.y); o1.z = f2bf(p1.z); o1.w = f2bf(p1.w);
            *(short4*)d = o0; *(short4*)(d + 4) = o1;
            __syncthreads();
        }
    }

    float p[4];
#pragma unroll
    for (int i = 0; i < 4; ++i) {
        float s = acc[0][i] * acc[0][i] + acc[1][i] * acc[1][i];
        s += __shfl_xor(s, 1);
        s += __shfl_xor(s, 2);
        s += __shfl_xor(s, 4);
        s += __shfl_xor(s, 8);
        p[i] = s;
    }
    __syncthreads();
    if (lc == 0) {
#pragma unroll
        for (int i = 0; i < 4; ++i) norms[wave][g * 4 + i] = p[i];
    }
    __syncthreads();

#pragma unroll
    for (int i = 0; i < 4; ++i) {
        const int rloc = g * 4 + i;
        const float tot = norms[0][rloc] + norms[1][rloc] + norms[2][rloc] + norms[3][rloc];
        const float inv = 1.f / fmaxf(sqrtf(tot), 1e-12f);
        const int r = row0 + rloc;
        short* dst = (r < NTOK_Q) ? (Qn + (size_t)r * DDIM)
                                  : (Dn + (size_t)(r - NTOK_Q) * DDIM);
        dst[wave * 32 + lc]      = f2bf(acc[0][i] * inv);
        dst[wave * 32 + 16 + lc] = f2bf(acc[1][i] * inv);
    }
}

// ---------------------------------------------------------------------------
// MaxSim v3: block = (c, 8 b's) = 256 q-rows x 256 n. D[c] staged once in LDS
// (64KB) via global_load_lds with pre-swizzled source (rule 21); each of 4
// waves computes 64 q-rows (2 b's) x 256 n, 256 MFMA/wave from LDS.
__global__ __launch_bounds__(256)
void maxsim(const short* __restrict__ Qn, const short* __restrict__ Dn,
            const unsigned short* __restrict__ maskT, float* __restrict__ out) {
    const int x  = blockIdx.x & 7;            // XCD (perf heuristic only)
    const int m8 = (blockIdx.x >> 3) & 7;
    const int bg = blockIdx.x >> 6;           // b-group (8 b's)
    const int c  = x * 8 + m8;                // all 8 bg's of a c on one XCD

    const int wave = threadIdx.x >> 6;
    const int lane = threadIdx.x & 63;
    const int g = lane >> 4, lc = lane & 15;

    __shared__ alignas(16) short Ds[LDOC * DDIM];   // 64KB, swizzled layout

    // stage D[c]: LDS slot s (row=s>>4, c16=s&15) <- global chunk (row, c16^(row&15))
    const short* dsrc = Dn + (size_t)c * LDOC * DDIM;
#pragma unroll
    for (int i = 0; i < 16; ++i) {
        const int slot = wave * 1024 + i * 64 + lane;          // 16B units
        const int row = slot >> 4, c16 = slot & 15;
        const short* gaddr = dsrc + row * DDIM + ((c16 ^ (row & 15)) * 8);
        __builtin_amdgcn_global_load_lds(
            (const __attribute__((address_space(1))) unsigned int*)gaddr,
            (__attribute__((address_space(3))) unsigned int*)(Ds + (size_t)(wave * 1024 + i * 64) * 8),
            16, 0, 0);
    }

    // Q fragments for this wave's 64 q-rows (= 2 b's), full K=128
    bf16x8 qf[4][4];
    const int qrow0 = bg * 256 + wave * 64;
#pragma unroll
    for (int m = 0; m < 4; ++m) {
        const short* qb = Qn + (size_t)(qrow0 + m * 16 + lc) * DDIM;
#pragma unroll
        for (int ks = 0; ks < 4; ++ks)
            qf[m][ks] = *(const bf16x8*)(qb + ks * 32 + g * 8);
    }

    const unsigned mbits = maskT[c * 16 + lc];    // bit nt = mask[c][nt*16+lc]

    __syncthreads();   // drains vmcnt (staging + q loads) then barrier

    float rmax[4][4];
#pragma unroll
    for (int m = 0; m < 4; ++m)
#pragma unroll
        for (int i = 0; i < 4; ++i) rmax[m][i] = -INFINITY;

    for (int nt = 0; nt < 16; ++nt) {
        bf16x8 bf[4];
        const int row = nt * 16 + lc;
#pragma unroll
        for (int ks = 0; ks < 4; ++ks) {
            const int c16 = (ks * 4 + g) ^ lc;     // read-side swizzle (matches source)
            bf[ks] = *(const bf16x8*)(Ds + row * DDIM + c16 * 8);
        }
        const bool on = (mbits >> nt) & 1;         // n = nt*16+lc == C-col lc
#pragma unroll
        for (int m = 0; m < 4; ++m) {
            f32x4 acc = (f32x4){0.f, 0.f, 0.f, 0.f};
#pragma unroll
            for (int ks = 0; ks < 4; ++ks)
                acc = __builtin_amdgcn_mfma_f32_16x16x32_bf16(qf[m][ks], bf[ks], acc, 0, 0, 0);
#pragma unroll
            for (int i = 0; i < 4; ++i)
                rmax[m][i] = on ? fmaxf(rmax[m][i], acc[i]) : rmax[m][i];
        }
    }

    // cross-col max (over lc lanes), then per-b row sums
    float s_lo = 0.f, s_hi = 0.f;
#pragma unroll
    for (int m = 0; m < 4; ++m) {
#pragma unroll
        for (int i = 0; i < 4; ++i) {
            float r = rmax[m][i];
            r = fmaxf(r, __shfl_xor(r, 1));
            r = fmaxf(r, __shfl_xor(r, 2));
            r = fmaxf(r, __shfl_xor(r, 4));
            r = fmaxf(r, __shfl_xor(r, 8));
            if (m < 2) s_lo += r; else s_hi += r;
        }
    }
    s_lo += __shfl_xor(s_lo, 16);
    s_lo += __shfl_xor(s_lo, 32);
    s_hi += __shfl_xor(s_hi, 16);
    s_hi += __shfl_xor(s_hi, 32);

    if (lane == 0) {
        const int b_lo = bg * 8 + wave * 2;
        out[(size_t)b_lo * NB + c]       = s_lo;
        out[(size_t)(b_lo + 1) * NB + c] = s_hi;
    }
}

// ---------------------------------------------------------------------------
extern "C" void kernel_launch(void* const* d_in, const int* in_sizes, int n_in,
                              void* d_out, int out_size, void* d_ws, size_t ws_size,
                              hipStream_t stream) {
    const float* Qh = (const float*)d_in[0];
    const float* Dh = (const float*)d_in[1];
    const float* W  = (const float*)d_in[2];
    const unsigned char* dm = (const unsigned char*)d_in[3];
    float* out = (float*)d_out;
    char* ws = (char*)d_ws;

    short*          Wbf   = (short*)(ws + WS_OFF_W);
    unsigned short* maskT = (unsigned short*)(ws + WS_OFF_MASK);
    short*          Qn    = (short*)(ws + WS_OFF_QN);
    short*          Dn    = (short*)(ws + WS_OFF_DN);

    prep<<<97, 256, 0, stream>>>(W, Wbf, dm, maskT);
    proj_norm<<<NTOK / 16, 256, 0, stream>>>(Qh, Dh, Wbf, Qn, Dn);
    maxsim<<<512, 256, 0, stream>>>(Qn, Dn, maskT, out);
}